// Round 2
// 96.540 us; speedup vs baseline: 1.0067x; 1.0067x over previous
//
#include <hip/hip_runtime.h>

#define B_DIM 256
#define IN_DIM 512
#define OUT_DIM 1024

typedef __attribute__((__ext_vector_type__(2))) float v2f;

// ---------- bit decode: [8] spike bits -> fp32 (exact E4M3 value) ----------
__device__ __forceinline__ float dec_pair(float4 a, float4 b) {
    int ef  = ((int)a.y << 3) | ((int)a.z << 2) | ((int)a.w << 1) | (int)b.x;
    int man = ((int)b.y << 2) | ((int)b.z << 1) | (int)b.w;
    float mag;
    if (ef > 0)
        mag = __uint_as_float(((unsigned)(ef + 120) << 23) | ((unsigned)man << 20));
    else
        mag = (float)man * 0.001953125f;  // man * 2^-9 (subnormal)
    return (a.x != 0.0f) ? -mag : mag;
}

// One dispatch decodes both x (v < 131072) and w (rest). Branch is uniform
// per block (131072 = 512 full blocks).
__global__ void k_decode(const float* __restrict__ xbits,
                         const float* __restrict__ wbits,
                         float* __restrict__ xf, float* __restrict__ wt) {
    int v = blockIdx.x * 256 + threadIdx.x;          // 0 .. 655359
    if (v < B_DIM * IN_DIM) {
        const float4* p = (const float4*)xbits + (size_t)v * 2;
        xf[v] = dec_pair(p[0], p[1]);
    } else {
        int u = v - B_DIM * IN_DIM;
        const float4* p = (const float4*)wbits + (size_t)u * 2;
        float val = dec_pair(p[0], p[1]);
        int o = u >> 9, i = u & 511;
        // wt layout [(i>>2)][o][i&3]: one coalesced dwordx4 per 4 K-steps in k_main
        wt[((size_t)(i >> 2) * OUT_DIM + o) * 4 + (i & 3)] = val;
    }
}

// ---------- encode fp32 (exact E4M3) -> [8] spike bits ----------
__device__ __forceinline__ void store8(float* __restrict__ out, int idx, float v) {
    unsigned au = __float_as_uint(v) & 0x7fffffffu;
    float sgn = (v < 0.0f) ? 1.0f : 0.0f;           // -0.0 -> sign bit 0, like ref
    int ef, man;
    if (au >= 0x3c800000u) {                         // |v| >= 2^-6 : normal
        ef  = (int)(au >> 23) - 120;                 // (exp-127)+7
        man = (int)((au >> 20) & 7u);
    } else {                                         // subnormal / zero
        ef  = 0;
        man = (int)(__uint_as_float(au) * 512.0f);   // exact multiple of 2^-9
    }
    float4 lo = make_float4(sgn,
                            (float)((ef >> 3) & 1), (float)((ef >> 2) & 1),
                            (float)((ef >> 1) & 1));
    float4 hi = make_float4((float)(ef & 1),
                            (float)((man >> 2) & 1), (float)((man >> 1) & 1),
                            (float)(man & 1));
    float4* op = (float4*)(out + (size_t)idx * 8);
    op[0] = lo;
    op[1] = hi;
}

// quantize both lanes of a v2f to exact E4M3 values (RNE, saturating)
__device__ __forceinline__ v2f qpk(v2f v) {
    int q = __builtin_amdgcn_cvt_pk_fp8_f32(v.x, v.y, 0, false);
    return __builtin_amdgcn_cvt_pk_f32_fp8(q, false);
}

// quantized product p = q(x * w) for two chains packed in a v2f
__device__ __forceinline__ v2f qprod(v2f xp, float wk) {
    v2f wv = {wk, wk};
    return qpk(xp * wv);
}

// ---------- main sequential-quantized accumulation ----------
// grid (OUT/64, B/8), block 256 = 4 waves. lane -> o, wave -> 2 b-rows
// packed into one v2f chain. x rows staged in LDS as interleaved
// {row0[i], row1[i]} pairs so ds_read_b128 (same-address broadcast,
// conflict-free) feeds 2 steps of both chains.
//
// This version: FULL unroll of the 64-group loop with direct indexing.
// - all LDS reads become imm-offset ds_read_b128 off one base (no rotation
//   v_movs, no guarded-prefetch branches)
// - per group, the 8 quantized products (independent of acc) are computed
//   before the 8-step serial add-chain, so the scheduler can overlap group
//   g+1's product pipeline with group g's dependent chain and hoist loads
//   as deep as register pressure allows.
// Numerics identical to the rolled version (same ops, same chain order).
__global__ __launch_bounds__(256) void k_main(const float* __restrict__ xf,
                                              const float* __restrict__ wt,
                                              float* __restrict__ out) {
    __shared__ float xs[8 * IN_DIM];                 // 16 KB: 4 wave regions
    int tid  = threadIdx.x;
    int lane = tid & 63;
    int wid  = tid >> 6;
    int o  = blockIdx.x * 64 + lane;
    int b0 = blockIdx.y * 8 + wid * 2;

    // ---- stage this wave's 2 x-rows as interleaved pairs ----
    {
        const float4* ra = (const float4*)(xf + (size_t)b0 * IN_DIM) + lane * 2;
        const float4* rb = (const float4*)(xf + (size_t)(b0 + 1) * IN_DIM) + lane * 2;
        float4 a0 = ra[0], a1 = ra[1];
        float4 c0 = rb[0], c1 = rb[1];
        float4* dst = (float4*)(xs + (size_t)wid * 2 * IN_DIM) + lane * 4;
        dst[0] = make_float4(a0.x, c0.x, a0.y, c0.y);
        dst[1] = make_float4(a0.z, c0.z, a0.w, c0.w);
        dst[2] = make_float4(a1.x, c1.x, a1.y, c1.y);
        dst[3] = make_float4(a1.z, c1.z, a1.w, c1.w);
    }
    __syncthreads();

    const float4* xls = (const float4*)(xs + (size_t)wid * 2 * IN_DIM);  // 256 f4
    const float4* wq  = (const float4*)wt + o;       // stride OUT_DIM f4 per i4

    v2f acc = {0.0f, 0.0f};                          // q(0 + p0) == p0: safe init

#pragma unroll
    for (int g = 0; g < 64; ++g) {                   // 64 groups x 8 k-steps
        float4 x0 = xls[4 * g + 0];
        float4 x1 = xls[4 * g + 1];
        float4 x2 = xls[4 * g + 2];
        float4 x3 = xls[4 * g + 3];
        float4 wa = wq[(size_t)(2 * g + 0) * OUT_DIM];
        float4 wb = wq[(size_t)(2 * g + 1) * OUT_DIM];
        const v2f* xp0 = (const v2f*)&x0;
        const v2f* xp1 = (const v2f*)&x1;
        const v2f* xp2 = (const v2f*)&x2;
        const v2f* xp3 = (const v2f*)&x3;
        // 8 independent quantized products (off the acc critical path)
        v2f p0 = qprod(xp0[0], wa.x);
        v2f p1 = qprod(xp0[1], wa.y);
        v2f p2 = qprod(xp1[0], wa.z);
        v2f p3 = qprod(xp1[1], wa.w);
        v2f p4 = qprod(xp2[0], wb.x);
        v2f p5 = qprod(xp2[1], wb.y);
        v2f p6 = qprod(xp3[0], wb.z);
        v2f p7 = qprod(xp3[1], wb.w);
        // serial quantized accumulation (the true dependency chain)
        acc = qpk(acc + p0);
        acc = qpk(acc + p1);
        acc = qpk(acc + p2);
        acc = qpk(acc + p3);
        acc = qpk(acc + p4);
        acc = qpk(acc + p5);
        acc = qpk(acc + p6);
        acc = qpk(acc + p7);
    }

    store8(out, b0 * OUT_DIM + o, acc.x);
    store8(out, (b0 + 1) * OUT_DIM + o, acc.y);
}

extern "C" void kernel_launch(void* const* d_in, const int* in_sizes, int n_in,
                              void* d_out, int out_size, void* d_ws, size_t ws_size,
                              hipStream_t stream) {
    const float* xb = (const float*)d_in[0];   // [256][512][8]
    const float* wb = (const float*)d_in[1];   // [1024][512][8]
    float* out = (float*)d_out;                // [256][1024][8]

    float* xf = (float*)d_ws;                        // 131072 floats
    float* wt = (float*)d_ws + B_DIM * IN_DIM;       // 524288 floats

    int total = B_DIM * IN_DIM + OUT_DIM * IN_DIM;   // 655360
    k_decode<<<dim3(total / 256), dim3(256), 0, stream>>>(xb, wb, xf, wt);

    dim3 grid(OUT_DIM / 64, B_DIM / 8);
    k_main<<<grid, dim3(256), 0, stream>>>(xf, wt, out);
}